// Round 12
// baseline (33.438 us; speedup 1.0000x reference)
//
#include <hip/hip_runtime.h>
#include <math.h>

// B=16, T=64, R=256, C=16, D=16, O(=in_dim)=16, NUM_ITERATIONS=3
//
// Factorization: u_hat[b,t,r,c,o] = Wsum[r,c,o]*usum[b,t]
//   Wsum[r,c,o] = sum_d W[r,c,d,o], usum[b,t] = sum_i ui[b,t,i]
// Per iter: cij = softmax_c(bij); S[c,o] = sum_r cij[r,c]*Wsum[r,c,o]
//   NS[c] = sum_o S^2; Ts[c] = sum_t us^2*squash_scale(us^2*NS[c])
//   bij[r,c] += (sum_o Wsum[r,c,o]*S[c,o]) * Ts[c]
// Output: v[b,t,c,o] = squash_scale(us^2*NS[c])*us*S[c,o]
//
// R11: k2 register-resident (Wsum in VGPRs, shfl_xor butterflies, LDS only
// for the bij<->cij transpose) took 43 -> 32.8us. R12: widen k1 16 -> 64
// blocks (4 r each) to spread the 4MB W pull over 4x CUs; k2 unchanged.

#define OFF_WT 0   // WsumT [c*16+o][r] : 256x256 floats

__device__ __forceinline__ float squash_scale(float n2) {
    return n2 / (1.0f + n2) * rsqrtf(n2 + 1e-9f);
}

// K1: WT[co][r] = sum_d W[r,c,d,o]. 64 blocks x 256 (4 r per block).
__global__ void __launch_bounds__(256) k1_prep(const float* __restrict__ W,
                                               float* __restrict__ ws) {
    __shared__ float sh[4 * 256];
    const int tid = threadIdx.x, bid = blockIdx.x;
    const int rr = tid >> 6;                 // local r (0..3)
    const int l = tid & 63;
    const int c = l >> 2, o4 = l & 3;
    const int r = bid * 4 + rr;
    const float* bp = W + r * 4096 + c * 256 + o4 * 4;
    float4 a = make_float4(0.f, 0.f, 0.f, 0.f);
#pragma unroll
    for (int d = 0; d < 16; ++d) {
        const float4 w = *(const float4*)(bp + d * 16);
        a.x += w.x; a.y += w.y; a.z += w.z; a.w += w.w;
    }
    const int co = c * 16 + o4 * 4;
    sh[rr * 256 + co + 0] = a.x;
    sh[rr * 256 + co + 1] = a.y;
    sh[rr * 256 + co + 2] = a.z;
    sh[rr * 256 + co + 3] = a.w;
    __syncthreads();
    // store WT[co2][bid*4 .. +3], thread co2 = tid
    {
        const int co2 = tid;
        float4 t;
        t.x = sh[0 * 256 + co2];
        t.y = sh[1 * 256 + co2];
        t.z = sh[2 * 256 + co2];
        t.w = sh[3 * 256 + co2];
        *(float4*)(ws + OFF_WT + co2 * 256 + bid * 4) = t;
    }
}

// K2: full routing, one block per b, Wsum register-resident. 16 x 1024.
__global__ void __launch_bounds__(1024, 4) k2_route(
    const float* __restrict__ ui, const float* __restrict__ ws,
    float* __restrict__ out)
{
    __shared__ float usum_sh[64];
    __shared__ __align__(16) float bijL[16][260];   // [c][r], 260%32=4 skew
    __shared__ __align__(16) float cijL[16][260];   // [c][r]
    __shared__ __align__(16) float S_sh[256];       // [c*16+o] (final S2)
    const int b = blockIdx.x, tid = threadIdx.x;
    const int w = tid >> 6, l = tid & 63;           // wave = c; lane owns r=4l..4l+3

    // wreg[o] = Wsum[4l..4l+3][w][o]  (float4 over r) — coalesced 1KB/wave/o
    float4 wreg[16];
#pragma unroll
    for (int o = 0; o < 16; ++o)
        wreg[o] = *(const float4*)(ws + OFF_WT + (w * 16 + o) * 256 + 4 * l);

    if (tid < 64) {
        const float4* u4 = (const float4*)(ui + b * 1024 + tid * 16);
        float4 a = u4[0], e = u4[1], f = u4[2], g = u4[3];
        usum_sh[tid] = ((a.x + a.y) + (a.z + a.w)) + ((e.x + e.y) + (e.z + e.w))
                     + ((f.x + f.y) + (f.z + f.w)) + ((g.x + g.y) + (g.z + g.w));
    }
    __syncthreads();                                 // (1) usum ready

    float S[16];
    float4 bijv = make_float4(0.f, 0.f, 0.f, 0.f);

#pragma unroll
    for (int it = 0; it < 3; ++it) {
        // ---- B: S[o] via registers + 64-lane butterfly ----
        if (it == 0) {
#pragma unroll
            for (int o = 0; o < 16; ++o)
                S[o] = (wreg[o].x + wreg[o].y) + (wreg[o].z + wreg[o].w);
        } else {
            const float4 c4 = *(const float4*)(&cijL[w][4 * l]);
#pragma unroll
            for (int o = 0; o < 16; ++o)
                S[o] = c4.x * wreg[o].x + c4.y * wreg[o].y
                     + c4.z * wreg[o].z + c4.w * wreg[o].w;
        }
#pragma unroll
        for (int off = 1; off < 64; off <<= 1)
#pragma unroll
            for (int o = 0; o < 16; ++o) S[o] += __shfl_xor(S[o], off, 64);
        if (it == 0)
#pragma unroll
            for (int o = 0; o < 16; ++o) S[o] *= (1.0f / 16.0f);

        if (it < 2) {
            // ---- Ts (wave-local): NS in regs, butterfly over t ----
            float ns = 0.f;
#pragma unroll
            for (int o = 0; o < 16; ++o) ns += S[o] * S[o];
            const float us = usum_sh[l];
            const float us2 = us * us;
            float ts = us2 * squash_scale(us2 * ns);
#pragma unroll
            for (int off = 1; off < 64; off <<= 1) ts += __shfl_xor(ts, off, 64);

            // ---- E (pure reg): bij[r=4l+k][w] += dot_o(W,S)*Ts ----
            float4 g4 = make_float4(0.f, 0.f, 0.f, 0.f);
#pragma unroll
            for (int o = 0; o < 16; ++o) {
                g4.x += wreg[o].x * S[o]; g4.y += wreg[o].y * S[o];
                g4.z += wreg[o].z * S[o]; g4.w += wreg[o].w * S[o];
            }
            bijv.x += g4.x * ts; bijv.y += g4.y * ts;
            bijv.z += g4.z * ts; bijv.w += g4.w * ts;
            *(float4*)(&bijL[w][4 * l]) = bijv;
            __syncthreads();                          // (2/4) bij visible

            // ---- softmax over c: thread (r=tid>>2, j=tid&3), 4-lane quads ----
            {
                const int r = tid >> 2, j = tid & 3;
                float v0 = bijL[4 * j + 0][r], v1 = bijL[4 * j + 1][r];
                float v2 = bijL[4 * j + 2][r], v3 = bijL[4 * j + 3][r];
                float m = fmaxf(fmaxf(v0, v1), fmaxf(v2, v3));
                m = fmaxf(m, __shfl_xor(m, 1, 4));
                m = fmaxf(m, __shfl_xor(m, 2, 4));
                const float e0 = __expf(v0 - m), e1 = __expf(v1 - m);
                const float e2 = __expf(v2 - m), e3 = __expf(v3 - m);
                float z = (e0 + e1) + (e2 + e3);
                z += __shfl_xor(z, 1, 4);
                z += __shfl_xor(z, 2, 4);
                const float inv = 1.0f / z;
                cijL[4 * j + 0][r] = e0 * inv;
                cijL[4 * j + 1][r] = e1 * inv;
                cijL[4 * j + 2][r] = e2 * inv;
                cijL[4 * j + 3][r] = e3 * inv;
            }
            __syncthreads();                          // (3/5) cij ready
        }
    }

    // publish S2 for cross-wave output
    if (l == 0) {
#pragma unroll
        for (int o = 0; o < 16; ++o) S_sh[w * 16 + o] = S[o];
    }
    __syncthreads();                                  // (6)

    // Output: v[b,t,c,o] = squash_scale(us^2*NS[c])*us*S2[c,o]; thread=(t,c)
    {
        const int t = tid >> 4, c = tid & 15;
        float ns = 0.f;
#pragma unroll
        for (int o = 0; o < 16; ++o) { const float s = S_sh[c * 16 + o]; ns += s * s; }
        const float us = usum_sh[t];
        const float n2 = us * us * ns;
        const float f = squash_scale(n2) * us;
        float4* o4 = (float4*)(out + (((b * 64 + t) * 16 + c) << 4));
        const float4* s4 = (const float4*)(S_sh + c * 16);
#pragma unroll
        for (int q = 0; q < 4; ++q) {
            const float4 sv = s4[q];
            float4 ov;
            ov.x = f * sv.x; ov.y = f * sv.y; ov.z = f * sv.z; ov.w = f * sv.w;
            o4[q] = ov;
        }
    }
}

extern "C" void kernel_launch(void* const* d_in, const int* in_sizes, int n_in,
                              void* d_out, int out_size, void* d_ws, size_t ws_size,
                              hipStream_t stream) {
    const float* ui = (const float*)d_in[0];   // [16,64,16]
    const float* W  = (const float*)d_in[1];   // [1,256,16,16,16]
    float* out = (float*)d_out;                // [16,64,16,16]
    float* ws  = (float*)d_ws;

    k1_prep<<<64, 256, 0, stream>>>(W, ws);
    k2_route<<<16, 1024, 0, stream>>>(ui, ws, out);
}

// Round 13
// 29.358 us; speedup vs baseline: 1.1390x; 1.1390x over previous
//
#include <hip/hip_runtime.h>
#include <math.h>

// B=16, T=64, R=256, C=16, D=16, O(=in_dim)=16, NUM_ITERATIONS=3
//
// Factorization: u_hat[b,t,r,c,o] = Wsum[r,c,o]*usum[b,t]
//   Wsum[r,c,o] = sum_d W[r,c,d,o], usum[b,t] = sum_i ui[b,t,i]
// Per iter: cij = softmax_c(bij); S[c,o] = sum_r cij[r,c]*Wsum[r,c,o]
//   NS[c] = sum_o S^2; Ts[c] = sum_t us^2*squash_scale(us^2*NS[c])
//   bij[r,c] += (sum_o Wsum[r,c,o]*S[c,o]) * Ts[c]
// Output: v[b,t,c,o] = squash_scale(us^2*NS[c])*us*S[c,o]
//
// R11: register-resident Wsum (lane l of wave w = Wsum[4l..4l+3][c=w][:]),
// shfl_xor butterflies, LDS only for bij<->cij transpose: 43 -> 32.8us.
// R13: barrier trim 7 -> 4. usum computed per-lane (t=lane) in every wave
// (redundant coalesced 4KB read, no LDS, no barrier); output written
// wave-locally (wave w owns c=w; S2/NS are register-resident post-butterfly)
// -> no S_sh publish, no final barrier.

#define OFF_WT 0   // WsumT [c*16+o][r] : 256x256 floats

__device__ __forceinline__ float squash_scale(float n2) {
    return n2 / (1.0f + n2) * rsqrtf(n2 + 1e-9f);
}

// K1: WT[co][r] = sum_d W[r,c,d,o]. 64 blocks x 256 (4 r per block).
__global__ void __launch_bounds__(256) k1_prep(const float* __restrict__ W,
                                               float* __restrict__ ws) {
    __shared__ float sh[4 * 256];
    const int tid = threadIdx.x, bid = blockIdx.x;
    const int rr = tid >> 6;                 // local r (0..3)
    const int l = tid & 63;
    const int c = l >> 2, o4 = l & 3;
    const int r = bid * 4 + rr;
    const float* bp = W + r * 4096 + c * 256 + o4 * 4;
    float4 a = make_float4(0.f, 0.f, 0.f, 0.f);
#pragma unroll
    for (int d = 0; d < 16; ++d) {
        const float4 w = *(const float4*)(bp + d * 16);
        a.x += w.x; a.y += w.y; a.z += w.z; a.w += w.w;
    }
    const int co = c * 16 + o4 * 4;
    sh[rr * 256 + co + 0] = a.x;
    sh[rr * 256 + co + 1] = a.y;
    sh[rr * 256 + co + 2] = a.z;
    sh[rr * 256 + co + 3] = a.w;
    __syncthreads();
    {
        const int co2 = tid;                 // store WT[co2][bid*4 .. +3]
        float4 t;
        t.x = sh[0 * 256 + co2];
        t.y = sh[1 * 256 + co2];
        t.z = sh[2 * 256 + co2];
        t.w = sh[3 * 256 + co2];
        *(float4*)(ws + OFF_WT + co2 * 256 + bid * 4) = t;
    }
}

// K2: full routing, one block per b, Wsum register-resident. 16 x 1024.
__global__ void __launch_bounds__(1024, 4) k2_route(
    const float* __restrict__ ui, const float* __restrict__ ws,
    float* __restrict__ out)
{
    __shared__ __align__(16) float bijL[16][260];   // [c][r], 260%32=4 skew
    __shared__ __align__(16) float cijL[16][260];   // [c][r]
    const int b = blockIdx.x, tid = threadIdx.x;
    const int w = tid >> 6, l = tid & 63;           // wave = c; lane owns r=4l..4l+3

    // wreg[o] = Wsum[4l..4l+3][w][o]  (float4 over r) — coalesced 1KB/wave/o
    float4 wreg[16];
#pragma unroll
    for (int o = 0; o < 16; ++o)
        wreg[o] = *(const float4*)(ws + OFF_WT + (w * 16 + o) * 256 + 4 * l);

    // per-lane usum for t = l (every wave redundantly; coalesced 4KB/wave)
    float us;
    {
        const float4* u4 = (const float4*)(ui + b * 1024 + l * 16);
        const float4 a = u4[0], e = u4[1], f = u4[2], g = u4[3];
        us = ((a.x + a.y) + (a.z + a.w)) + ((e.x + e.y) + (e.z + e.w))
           + ((f.x + f.y) + (f.z + f.w)) + ((g.x + g.y) + (g.z + g.w));
    }

    float S[16];
    float4 bijv = make_float4(0.f, 0.f, 0.f, 0.f);

#pragma unroll
    for (int it = 0; it < 3; ++it) {
        // ---- B: S[o] via registers + 64-lane butterfly ----
        if (it == 0) {
#pragma unroll
            for (int o = 0; o < 16; ++o)
                S[o] = (wreg[o].x + wreg[o].y) + (wreg[o].z + wreg[o].w);
        } else {
            const float4 c4 = *(const float4*)(&cijL[w][4 * l]);
#pragma unroll
            for (int o = 0; o < 16; ++o)
                S[o] = c4.x * wreg[o].x + c4.y * wreg[o].y
                     + c4.z * wreg[o].z + c4.w * wreg[o].w;
        }
#pragma unroll
        for (int off = 1; off < 64; off <<= 1)
#pragma unroll
            for (int o = 0; o < 16; ++o) S[o] += __shfl_xor(S[o], off, 64);
        if (it == 0)
#pragma unroll
            for (int o = 0; o < 16; ++o) S[o] *= (1.0f / 16.0f);

        if (it < 2) {
            // ---- Ts (wave-local): NS in regs, butterfly over t=lane ----
            float ns = 0.f;
#pragma unroll
            for (int o = 0; o < 16; ++o) ns += S[o] * S[o];
            const float us2 = us * us;
            float ts = us2 * squash_scale(us2 * ns);
#pragma unroll
            for (int off = 1; off < 64; off <<= 1) ts += __shfl_xor(ts, off, 64);

            // ---- E (pure reg): bij[r=4l+k][w] += dot_o(W,S)*Ts ----
            float4 g4 = make_float4(0.f, 0.f, 0.f, 0.f);
#pragma unroll
            for (int o = 0; o < 16; ++o) {
                g4.x += wreg[o].x * S[o]; g4.y += wreg[o].y * S[o];
                g4.z += wreg[o].z * S[o]; g4.w += wreg[o].w * S[o];
            }
            bijv.x += g4.x * ts; bijv.y += g4.y * ts;
            bijv.z += g4.z * ts; bijv.w += g4.w * ts;
            *(float4*)(&bijL[w][4 * l]) = bijv;
            __syncthreads();                          // (1/3) bij visible

            // ---- softmax over c: thread (r=tid>>2, j=tid&3), 4-lane quads ----
            {
                const int r = tid >> 2, j = tid & 3;
                float v0 = bijL[4 * j + 0][r], v1 = bijL[4 * j + 1][r];
                float v2 = bijL[4 * j + 2][r], v3 = bijL[4 * j + 3][r];
                float m = fmaxf(fmaxf(v0, v1), fmaxf(v2, v3));
                m = fmaxf(m, __shfl_xor(m, 1, 4));
                m = fmaxf(m, __shfl_xor(m, 2, 4));
                const float e0 = __expf(v0 - m), e1 = __expf(v1 - m);
                const float e2 = __expf(v2 - m), e3 = __expf(v3 - m);
                float z = (e0 + e1) + (e2 + e3);
                z += __shfl_xor(z, 1, 4);
                z += __shfl_xor(z, 2, 4);
                const float inv = 1.0f / z;
                cijL[4 * j + 0][r] = e0 * inv;
                cijL[4 * j + 1][r] = e1 * inv;
                cijL[4 * j + 2][r] = e2 * inv;
                cijL[4 * j + 3][r] = e3 * inv;
            }
            __syncthreads();                          // (2/4) cij ready
        }
    }

    // ---- Output (wave-local): wave w owns c=w, lane l owns t=l ----
    // v[b,t=l,c=w,o] = squash_scale(us^2*NS)*us*S2[o]; S2/NS in registers.
    {
        float ns = 0.f;
#pragma unroll
        for (int o = 0; o < 16; ++o) ns += S[o] * S[o];
        const float n2 = us * us * ns;
        const float f = squash_scale(n2) * us;
        float4* o4 = (float4*)(out + (((b * 64 + l) * 16 + w) << 4));
#pragma unroll
        for (int q = 0; q < 4; ++q) {
            float4 ov;
            ov.x = f * S[q * 4 + 0];
            ov.y = f * S[q * 4 + 1];
            ov.z = f * S[q * 4 + 2];
            ov.w = f * S[q * 4 + 3];
            o4[q] = ov;
        }
    }
}

extern "C" void kernel_launch(void* const* d_in, const int* in_sizes, int n_in,
                              void* d_out, int out_size, void* d_ws, size_t ws_size,
                              hipStream_t stream) {
    const float* ui = (const float*)d_in[0];   // [16,64,16]
    const float* W  = (const float*)d_in[1];   // [1,256,16,16,16]
    float* out = (float*)d_out;                // [16,64,16,16]
    float* ws  = (float*)d_ws;

    k1_prep<<<64, 256, 0, stream>>>(W, ws);
    k2_route<<<16, 1024, 0, stream>>>(ui, ws, out);
}